// Round 6
// baseline (330.681 us; speedup 1.0000x reference)
//
#include <hip/hip_runtime.h>

#define N_NODES 100000
#define N_EDGES 800000
#define NF 81
#define NB 22
#define OC 64
#define SCAN_CHUNK 1024
#define SCAN_BLOCKS ((N_NODES + SCAN_CHUNK - 1) / SCAN_CHUNK)   // 98

typedef __attribute__((ext_vector_type(8))) short bf16x8;
typedef __attribute__((ext_vector_type(4))) float f32x4;

#if defined(__has_builtin)
#if __has_builtin(__builtin_amdgcn_fdot2_f32_bf16)
#define HAVE_FDOT2 1
#endif
#endif

#ifdef HAVE_FDOT2
typedef __attribute__((ext_vector_type(2))) __bf16 bfv2;
#endif

// dot2: c += lo(a)*lo(b) + hi(a)*hi(b), operands are packed bf16 pairs
__device__ inline float dot2b(unsigned a, unsigned b, float c) {
#ifdef HAVE_FDOT2
    return __builtin_amdgcn_fdot2_f32_bf16(__builtin_bit_cast(bfv2, a),
                                           __builtin_bit_cast(bfv2, b), c, false);
#else
    return c + __uint_as_float(a << 16)         * __uint_as_float(b << 16)
             + __uint_as_float(a & 0xffff0000u) * __uint_as_float(b & 0xffff0000u);
#endif
}

// round-to-nearest-even fp32 -> bf16 (high part), returns residual in rest
__device__ inline unsigned short bfsplit(float v, float& rest) {
    const unsigned b = __float_as_uint(v);
    const unsigned short h = (unsigned short)((b + 0x7fffu + ((b >> 16) & 1u)) >> 16);
    rest = v - __uint_as_float(((unsigned)h) << 16);
    return h;
}

// ---------------------------------------------------------------------------
// Build B^T in bf16 hi/lo: BT[c][k], c in [0,128), k in [0,96).
// Written into scratch aliasing the head of the recA region (stream-ordered:
// k_prep overwrites recA only after k_node_mfma has consumed B^T).
__global__ void k_wprep(const float* __restrict__ w_s, const float* __restrict__ w_n,
                        short* __restrict__ bt)
{
    const int tid = blockIdx.x * blockDim.x + threadIdx.x;
    if (tid >= 128 * 96) return;
    const int c = tid / 96;
    const int k = tid - c * 96;
    float v = 0.f;
    if (k < NF) v = (c < OC) ? w_s[k * OC + c] : w_n[k * OC + (c - OC)];
    float rest, dummy;
    const unsigned short h = bfsplit(v, rest);
    const unsigned short l = bfsplit(rest, dummy);
    bt[c * 96 + k]               = (short)h;          // BT_hi
    bt[128 * 96 + c * 96 + k]    = (short)l;          // BT_lo
}

// ---------------------------------------------------------------------------
// Node GEMM on matrix cores: [out | pb] = feat @ [w_s | w_n[:81]]
// Split-bf16 3-pass MFMA (Ah*Bh + Ah*Bl + Al*Bh) -> ~2^-17 relative error.
__global__ __launch_bounds__(256) void k_node_mfma(
    const float* __restrict__ feat, const short* __restrict__ bt,
    float* __restrict__ out, float* __restrict__ pb, float4* __restrict__ xyz)
{
    __shared__ short shA[2 * 64 * 104];               // hi at 0, lo at 6656 (26.6 KB)
    const int t    = threadIdx.x;
    const int lane = t & 63;
    const int w    = t >> 6;
    const int n0   = blockIdx.x * 64;

    // ---- B fragments from global B^T (L2-resident, 16B-aligned b128 loads)
    const int krow = (lane >> 4) * 8;                 // k offset within 32-k tile
    bf16x8 Bh[3][2], Bl[3][2];
#pragma unroll
    for (int kt = 0; kt < 3; ++kt)
#pragma unroll
        for (int c = 0; c < 2; ++c) {
            const int col = w * 32 + c * 16 + (lane & 15);
            const int off = col * 96 + kt * 32 + krow;
            Bh[kt][c] = *(const bf16x8*)(bt + off);
            Bl[kt][c] = *(const bf16x8*)(bt + 128 * 96 + off);
        }

    // ---- stage A (64 rows x 81 k) as bf16 hi/lo into LDS
    const long gbase = (long)n0 * NF;
    const long gmax  = (long)N_NODES * NF;
    for (int j = t; j < (64 * NF) / 4; j += 256) {    // 1296 float4s
        const int flat = j * 4;
        float v[4];
        if (gbase + flat + 3 < gmax) {
            const float4 q = *(const float4*)(feat + gbase + flat);
            v[0] = q.x; v[1] = q.y; v[2] = q.z; v[3] = q.w;
        } else {
#pragma unroll
            for (int i = 0; i < 4; ++i)
                v[i] = (gbase + flat + i < gmax) ? feat[gbase + flat + i] : 0.f;
        }
#pragma unroll
        for (int i = 0; i < 4; ++i) {
            const int fi  = flat + i;
            const int row = (int)((unsigned)fi / 81u);
            const int k   = fi - row * 81;
            float rest, dummy;
            const unsigned short h = bfsplit(v[i], rest);
            const unsigned short l = bfsplit(rest, dummy);
            shA[row * 104 + k]        = (short)h;
            shA[6656 + row * 104 + k] = (short)l;
        }
    }
    // zero K padding 81..96 (frags read up to k=95)
    for (int j = t; j < 64 * 16; j += 256) {
        const int row = j >> 4, k = NF + (j & 15);
        shA[row * 104 + k] = 0;
        shA[6656 + row * 104 + k] = 0;
    }

    // xyz in exact fp32 (distance path must stay fp32-accurate)
    if (t < 64 && n0 + t < N_NODES) {
        const float* fp = feat + (long)(n0 + t) * NF;
        xyz[n0 + t] = make_float4(fp[0], fp[1], fp[2], 0.f);
    }
    __syncthreads();

    // ---- MFMA: 4 row-tiles x 2 col-tiles x 3 k-tiles x 3 passes
    f32x4 acc[4][2];
#pragma unroll
    for (int rt = 0; rt < 4; ++rt)
#pragma unroll
        for (int c = 0; c < 2; ++c)
            acc[rt][c] = (f32x4){0.f, 0.f, 0.f, 0.f};

#pragma unroll
    for (int kt = 0; kt < 3; ++kt) {
        bf16x8 Ah[4], Al[4];
#pragma unroll
        for (int rt = 0; rt < 4; ++rt) {
            const int o = (rt * 16 + (lane & 15)) * 104 + kt * 32 + krow;
            Ah[rt] = *(const bf16x8*)(shA + o);
            Al[rt] = *(const bf16x8*)(shA + 6656 + o);
        }
#pragma unroll
        for (int rt = 0; rt < 4; ++rt)
#pragma unroll
            for (int c = 0; c < 2; ++c) {
                f32x4 a = acc[rt][c];
                a = __builtin_amdgcn_mfma_f32_16x16x32_bf16(Ah[rt], Bh[kt][c], a, 0, 0, 0);
                a = __builtin_amdgcn_mfma_f32_16x16x32_bf16(Ah[rt], Bl[kt][c], a, 0, 0, 0);
                a = __builtin_amdgcn_mfma_f32_16x16x32_bf16(Al[rt], Bh[kt][c], a, 0, 0, 0);
                acc[rt][c] = a;
            }
    }

    // ---- epilogue: D layout col=lane&15, row=(lane>>4)*4+reg (verified map)
    const int c0    = w * 32 + (lane & 15);
    float* db       = (w < 2) ? out : pb;
    const int cbase = (w < 2) ? c0 : c0 - OC;
    const int r0    = (lane >> 4) * 4;
#pragma unroll
    for (int rt = 0; rt < 4; ++rt)
#pragma unroll
        for (int c = 0; c < 2; ++c)
#pragma unroll
            for (int reg = 0; reg < 4; ++reg) {
                const int node = n0 + rt * 16 + r0 + reg;
                if (node < N_NODES)
                    db[(long)node * OC + cbase + c * 16] = acc[rt][c][reg];
            }
}

// ---------------------------------------------------------------------------
// Histogram + rank capture: rank[e] = arrival index of edge e within src[e].
__global__ void k_hist(const int* __restrict__ src, int* __restrict__ cnt,
                       int* __restrict__ rank) {
    const int e = blockIdx.x * blockDim.x + threadIdx.x;
    if (e < N_EDGES) rank[e] = atomicAdd(&cnt[src[e]], 1);
}

__global__ __launch_bounds__(256) void k_scan_blk(
    const int* __restrict__ cnt, int* __restrict__ row, int* __restrict__ bsum)
{
    __shared__ int sh[256];
    const int t = threadIdx.x;
    const int base = blockIdx.x * SCAN_CHUNK + t * 4;
    int c0 = 0, c1 = 0, c2 = 0, c3 = 0;
    if (base + 3 < N_NODES) {
        const int4 c = *(const int4*)(cnt + base);
        c0 = c.x; c1 = c.y; c2 = c.z; c3 = c.w;
    } else {
        if (base + 0 < N_NODES) c0 = cnt[base + 0];
        if (base + 1 < N_NODES) c1 = cnt[base + 1];
        if (base + 2 < N_NODES) c2 = cnt[base + 2];
    }
    const int s = c0 + c1 + c2 + c3;
    sh[t] = s;
    __syncthreads();
    for (int off = 1; off < 256; off <<= 1) {
        int v = sh[t];
        int a = (t >= off) ? sh[t - off] : 0;
        __syncthreads();
        sh[t] = v + a;
        __syncthreads();
    }
    const int excl = sh[t] - s;
    if (t == 255) bsum[blockIdx.x] = sh[255];
    if (base + 3 < N_NODES) {
        int4 r;
        r.x = excl; r.y = excl + c0; r.z = excl + c0 + c1; r.w = excl + c0 + c1 + c2;
        *(int4*)(row + base) = r;
    } else {
        int e = excl;
        if (base + 0 < N_NODES) { row[base + 0] = e; e += c0; }
        if (base + 1 < N_NODES) { row[base + 1] = e; e += c1; }
        if (base + 2 < N_NODES) { row[base + 2] = e; }
    }
}

__global__ void k_scan_top(int* __restrict__ bsum, int* __restrict__ row) {
    __shared__ int sh[128];
    const int t = threadIdx.x;
    const int v = (t < SCAN_BLOCKS) ? bsum[t] : 0;
    sh[t] = v;
    __syncthreads();
    for (int off = 1; off < 128; off <<= 1) {
        int x = sh[t];
        int a = (t >= off) ? sh[t - off] : 0;
        __syncthreads();
        sh[t] = x + a;
        __syncthreads();
    }
    if (t < SCAN_BLOCKS) bsum[t] = sh[t] - v;
    if (t == 127) row[N_NODES] = sh[127];
}

__global__ __launch_bounds__(256) void k_scan_add(
    int* __restrict__ row, const int* __restrict__ bsum)
{
    const int off = bsum[blockIdx.x];
    const int base = blockIdx.x * SCAN_CHUNK + threadIdx.x * 4;
    if (base + 3 < N_NODES) {
        int4 r = *(const int4*)(row + base);
        r.x += off; r.y += off; r.z += off; r.w += off;
        *(int4*)(row + base) = r;
    } else {
#pragma unroll
        for (int k = 0; k < 4; ++k)
            if (base + k < N_NODES)
                row[base + k] += off;
    }
}

// ---------------------------------------------------------------------------
// Permutation scatter: the ONLY scattered write left (4B/edge).
// perm[row[src[e]] + rank[e]] = e  -> src-sorted edge order for k_gather.
__global__ void k_perm(const int* __restrict__ src, const int* __restrict__ rank,
                       const int* __restrict__ row, int* __restrict__ perm) {
    const int e = blockIdx.x * blockDim.x + threadIdx.x;
    if (e < N_EDGES) perm[row[src[e]] + rank[e]] = e;
}

// ---------------------------------------------------------------------------
// Record build in EDGE order (fully coalesced writes, no RMW amplification):
// recA[e*12 + 0..10] = bond bf16 pairs, [11] = inv (f32). recB[e] = dst.
__device__ inline unsigned pk_bf16(float a, float b) {
    const unsigned ua = (__float_as_uint(a) + 0x8000u) >> 16;
    const unsigned ub = (__float_as_uint(b) + 0x8000u) & 0xffff0000u;
    return ua | ub;
}

__global__ __launch_bounds__(256) void k_prep(
    const int* __restrict__ src, const int* __restrict__ dst,
    const float* __restrict__ bond, const float4* __restrict__ xyz,
    unsigned* __restrict__ recA, unsigned* __restrict__ recB)
{
    const int e = blockIdx.x * blockDim.x + threadIdx.x;
    if (e >= N_EDGES) return;
    const int s = src[e];
    const int d = dst[e];
    const float4 a = xyz[s], b = xyz[d];          // L2-resident gathers
    const float dx = a.x - b.x, dy = a.y - b.y, dz = a.z - b.z;
    const float d2 = dx * dx + dy * dy + dz * dz;
    const float inv = (d2 > 0.f) ? __builtin_amdgcn_rcpf(d2) : 1.0e4f;

    float2 bv[11];
    const float2* bp = (const float2*)(bond + (long)e * NB);   // 88B, 8B-aligned
#pragma unroll
    for (int j = 0; j < 11; ++j) bv[j] = bp[j];

    unsigned p[11];
#pragma unroll
    for (int j = 0; j < 11; ++j) p[j] = pk_bf16(bv[j].x, bv[j].y);

    unsigned* r = recA + (size_t)e * 12;          // coalesced 48B store
    *(uint4*)(r)     = make_uint4(p[0], p[1], p[2], p[3]);
    *(uint4*)(r + 4) = make_uint4(p[4], p[5], p[6], p[7]);
    *(uint4*)(r + 8) = make_uint4(p[8], p[9], p[10], __float_as_uint(inv));
    recB[e] = (unsigned)d;                        // coalesced 4B store
}

// ---------------------------------------------------------------------------
// Gather: wave per node, lane = channel, NO atomics.
// Edge order via perm[i] (sequential read, SGPR-broadcast); record reads are
// wave-uniform random 48B hits in L2/L3 (records = 41.6 MB, L3-resident).
__global__ __launch_bounds__(256) void k_gather(
    const int* __restrict__ row, const int* __restrict__ perm,
    const unsigned* __restrict__ recA, const unsigned* __restrict__ recB,
    const float* __restrict__ w_n, const float* __restrict__ pb,
    const float4* __restrict__ xyz, float* __restrict__ out)
{
    const int lane = threadIdx.x & 63;
    const int wid  = (int)((blockIdx.x * blockDim.x + threadIdx.x) >> 6);
    if (wid >= N_NODES) return;
    const int n = __builtin_amdgcn_readfirstlane(wid);

    // per-lane w_n bond columns, packed as bf16 pairs (matches record packing)
    unsigned wp[11];
#pragma unroll
    for (int j = 0; j < 11; ++j)
        wp[j] = pk_bf16(w_n[(NF + 2 * j) * OC + lane],
                        w_n[(NF + 2 * j + 1) * OC + lane]);
    const float w0 = w_n[0 * OC + lane];
    const float w1 = w_n[1 * OC + lane];
    const float w2 = w_n[2 * OC + lane];

    const int rs = row[n], re = row[n + 1];
    const float4 xs = xyz[n];
    const float pa = pb[(long)n * OC + lane]
                   - (xs.x * w0 + xs.y * w1 + xs.z * w2);

    float acc = 0.f;
    int i = rs;

    // ---- main loop: 4 edges in flight
    for (; i + 4 <= re; i += 4) {
        int pe[4];
#pragma unroll
        for (int u = 0; u < 4; ++u)
            pe[u] = __builtin_amdgcn_readfirstlane(perm[i + u]);
        unsigned P[4][12];
        unsigned db[4];
#pragma unroll
        for (int u = 0; u < 4; ++u) {
            const unsigned* r = recA + (size_t)pe[u] * 12;
#pragma unroll
            for (int j = 0; j < 12; ++j) P[u][j] = r[j];   // s_load batch
            db[u] = recB[pe[u]];
        }
        float pbt[4];
#pragma unroll
        for (int u = 0; u < 4; ++u)
            pbt[u] = pb[(long)(int)db[u] * OC + lane];
        float c[4];
#pragma unroll
        for (int u = 0; u < 4; ++u)
            c[u] = __uint_as_float(P[u][11]) * (pa + pbt[u]);
#pragma unroll
        for (int j = 0; j < 11; ++j)
#pragma unroll
            for (int u = 0; u < 4; ++u)
                c[u] = dot2b(P[u][j], wp[j], c[u]);
        acc += (c[0] + c[1]) + (c[2] + c[3]);
    }

    // ---- tail: one edge at a time
    for (; i < re; ++i) {
        const int pe = __builtin_amdgcn_readfirstlane(perm[i]);
        const unsigned* r = recA + (size_t)pe * 12;
        unsigned p[12];
#pragma unroll
        for (int j = 0; j < 12; ++j) p[j] = r[j];
        const unsigned dbt = recB[pe];
        const float pbt = pb[(long)(int)dbt * OC + lane];
        float c = __uint_as_float(p[11]) * (pa + pbt);
#pragma unroll
        for (int j = 0; j < 11; ++j)
            c = dot2b(p[j], wp[j], c);
        acc += c;
    }

    out[(long)n * OC + lane] += acc;
}

// ---------------------------------------------------------------------------
extern "C" void kernel_launch(void* const* d_in, const int* in_sizes, int n_in,
                              void* d_out, int out_size, void* d_ws, size_t ws_size,
                              hipStream_t stream) {
    const float* feat = (const float*)d_in[0];
    const float* bond = (const float*)d_in[1];
    const float* w_s  = (const float*)d_in[2];
    const float* w_n  = (const float*)d_in[3];
    const int*   src  = (const int*)d_in[4];
    const int*   dstv = (const int*)d_in[5];
    float* out = (float*)d_out;

    // workspace layout (16B-aligned), ~76.0 MB total
    char* base = (char*)d_ws;
    float*    pb     = (float*)   (base);                 // 25,600,000
    float4*   xyz    = (float4*)  (base + 25600000);      //  1,600,000
    int*      row    = (int*)     (base + 27200000);      //    400,016
    int*      cnt    = (int*)     (base + 27600016);      //    400,000
    int*      rank   = (int*)     (base + 28000016);      //  3,200,000
    int*      bsum   = (int*)     (base + 31200016);      //        560 (pad)
    unsigned* recA   = (unsigned*)(base + 31200640);      // 38,400,000 (48B/edge)
    unsigned* recB   = (unsigned*)(base + 69600640);      //  3,200,000 (dst ids)
    int*      perm   = (int*)     (base + 72800640);      //  3,200,000
    // B^T bf16 hi/lo scratch aliases the head of recA (49,152 B).
    // Safe: k_node_mfma (reader) completes before k_prep (writer) on the stream.
    short*    btw    = (short*)recA;

    hipMemsetAsync(cnt, 0, N_NODES * sizeof(int), stream);

    k_wprep   <<<48, 256, 0, stream>>>(w_s, w_n, btw);
    k_node_mfma<<<(N_NODES + 63) / 64, 256, 0, stream>>>(feat, btw, out, pb, xyz);
    k_prep    <<<(N_EDGES + 255) / 256, 0 ? 0 : 256, 0, stream>>>(src, dstv, bond,
                                                                  xyz, recA, recB);
    k_hist    <<<(N_EDGES + 255) / 256, 256, 0, stream>>>(src, cnt, rank);
    k_scan_blk<<<SCAN_BLOCKS, 256, 0, stream>>>(cnt, row, bsum);
    k_scan_top<<<1, 128, 0, stream>>>(bsum, row);
    k_scan_add<<<SCAN_BLOCKS, 256, 0, stream>>>(row, bsum);
    k_perm    <<<(N_EDGES + 255) / 256, 256, 0, stream>>>(src, rank, row, perm);
    k_gather  <<<(N_NODES * 64 + 255) / 256, 256, 0, stream>>>(row, perm, recA,
                                                               recB, w_n, pb,
                                                               xyz, out);
}